// Round 8
// baseline (6694.671 us; speedup 1.0000x reference)
//
#include <hip/hip_runtime.h>
#include <hip/hip_bf16.h>

#define B_ 128
#define C_ 1024
#define LD1 3392
#define SL1 (B_*LD1)
#define NBLK 256

typedef float f32x4 __attribute__((ext_vector_type(4)));
typedef short bf16x8 __attribute__((ext_vector_type(8)));

__device__ inline unsigned short f2bf(float x){
  unsigned u = __float_as_uint(x);
  return (unsigned short)((u + 0x7fffu + ((u>>16)&1u)) >> 16);
}
__device__ inline unsigned long long pack4(float a,float b,float c,float d){
  unsigned lo = (unsigned)f2bf(a) | ((unsigned)f2bf(b)<<16);
  unsigned hi = (unsigned)f2bf(c) | ((unsigned)f2bf(d)<<16);
  return (unsigned long long)lo | ((unsigned long long)hi<<32);
}
__device__ inline float bf2f(unsigned short b){ return __uint_as_float(((unsigned)b)<<16); }
__device__ inline float sigm(float x){ return 1.f/(1.f+expf(-x)); }
__device__ inline float wsum(float v){
  #pragma unroll
  for(int o=32;o;o>>=1) v += __shfl_xor(v,o);
  return v;
}
__device__ inline int swz64(int r,int c){ return (r*64+c) ^ ((r&7)<<3); }
__device__ inline int swz128(int r,int c){ return (r*128+c) ^ ((r&7)<<3); }

struct Par {
  const float *in_BC,*txs,*tstate,*cxs,*lntw,*lntb,*lerp8,*bon;
  const float *Wr,*Wk,*Wv,*Wo,*ksW,*ksb,*vsW,*vsb;
  const float *vA,*vB,*vbias,*aA,*aB,*abias,*dA,*dB,*dbias,*gA,*gB;
  const float *gnw,*gnb,*lncw,*lncb,*lkc,*cWk,*cWv;
  float *out;
  float *xbuf,*g1s,*vm,*afin,*wfin,*gfin,*v0;
  unsigned short *mixed,*ybuf,*mixc,*hs;
  unsigned *bar;
};

// ---- device-scope grid barrier: monotonic counter, no reset race ----
__device__ __forceinline__ void gbar(unsigned* cnt, unsigned& crossing){
  __syncthreads();
  if (threadIdx.x == 0){
    __threadfence();                       // release all prior global writes
    atomicAdd(cnt, 1u);                    // device-scope (m20)
    ++crossing;
    unsigned target = NBLK * crossing;
    while (__hip_atomic_load(cnt, __ATOMIC_ACQUIRE, __HIP_MEMORY_SCOPE_AGENT) < target)
      __builtin_amdgcn_s_sleep(1);
    __threadfence();                       // acquire: invalidate L1 before consuming
  }
  __syncthreads();
}

// ---- r1-proven direct-stage GEMM core: M=128, N=32, BK=64 ----
// AMODE 0: A bf16.  AMODE 1: A = relu^2(bf16 slab0 + bf16 slab1).
// OUTM 0: f32 store. 1: f32 atomic-add. 2: bf16 store.
template<int AMODE, int OUTM>
__device__ void gemm32(unsigned short* lA, unsigned short* lB,
    const unsigned short* __restrict__ A0, const unsigned short* __restrict__ A1, int lda,
    const float* __restrict__ W, int ldw, int wcol, int wtrans,
    float* __restrict__ outf, unsigned short* __restrict__ out16,
    int ldo, int ocol, int nvalid, int kt0, int kIters)
{
  int tid=threadIdx.x, lane=tid&63, w=tid>>6, lo=lane&15, hi=lane>>4;
  f32x4 acc[2][2] = {};
  for (int kb=0;kb<kIters;++kb){
    int k0 = kt0 + kb*64;
    #pragma unroll
    for (int p=0;p<8;++p){
      int idx = tid + p*256; int m = idx>>4; int c4 = (idx&15)<<2;
      unsigned long long v;
      if constexpr (AMODE==1){
        unsigned long long u0 = *(const unsigned long long*)(A0 + (size_t)m*lda + k0 + c4);
        unsigned long long u1 = *(const unsigned long long*)(A1 + (size_t)m*lda + k0 + c4);
        float e[4];
        #pragma unroll
        for (int j=0;j<4;++j){
          float s = bf2f((unsigned short)(u0>>(16*j))) + bf2f((unsigned short)(u1>>(16*j)));
          s = fmaxf(s,0.f); e[j] = s*s;
        }
        v = pack4(e[0],e[1],e[2],e[3]);
      } else {
        v = *(const unsigned long long*)(A0 + (size_t)m*lda + k0 + c4);
      }
      *(unsigned long long*)&lA[swz64(m,c4)] = v;
    }
    int n = tid&31, kp = tid>>5;
    #pragma unroll
    for (int p=0;p<4;++p){
      int kl = p*16 + kp*2;
      float w0=0.f, w1=0.f;
      if (!wtrans){
        const float* wp = W + (size_t)(k0+kl)*ldw + wcol + n;
        w0 = wp[0]; w1 = wp[ldw];
      } else if (n < 16){
        const float* wp = W + (size_t)n*1024 + k0 + kl;
        w0 = wp[0]; w1 = wp[1];
      }
      unsigned pk = (unsigned)f2bf(w0) | ((unsigned)f2bf(w1)<<16);
      *(unsigned*)&lB[swz64(n,kl)] = pk;
    }
    __syncthreads();
    #pragma unroll
    for (int ks=0;ks<2;++ks){
      int kk = ks*32 + hi*8;
      bf16x8 a0 = *(const bf16x8*)&lA[swz64(w*32+lo, kk)];
      bf16x8 a1 = *(const bf16x8*)&lA[swz64(w*32+16+lo, kk)];
      bf16x8 b0 = *(const bf16x8*)&lB[swz64(lo, kk)];
      bf16x8 b1 = *(const bf16x8*)&lB[swz64(16+lo, kk)];
      acc[0][0] = __builtin_amdgcn_mfma_f32_16x16x32_bf16(a0,b0,acc[0][0],0,0,0);
      acc[0][1] = __builtin_amdgcn_mfma_f32_16x16x32_bf16(a0,b1,acc[0][1],0,0,0);
      acc[1][0] = __builtin_amdgcn_mfma_f32_16x16x32_bf16(a1,b0,acc[1][0],0,0,0);
      acc[1][1] = __builtin_amdgcn_mfma_f32_16x16x32_bf16(a1,b1,acc[1][1],0,0,0);
    }
    __syncthreads();
  }
  #pragma unroll
  for (int mf=0;mf<2;++mf)
  #pragma unroll
  for (int nf=0;nf<2;++nf){
    int cl = nf*16 + lo;
    if (cl < nvalid){
      #pragma unroll
      for (int i=0;i<4;++i){
        int row = w*32 + mf*16 + hi*4 + i;
        size_t o = (size_t)row*ldo + ocol + cl;
        if constexpr (OUTM==0) outf[o] = acc[mf][nf][i];
        else if constexpr (OUTM==1) unsafeAtomicAdd(&outf[o], acc[mf][nf][i]);
        else out16[o] = f2bf(acc[mf][nf][i]);
      }
    }
  }
}

__global__ void __launch_bounds__(256) net_k(Par p){
  __shared__ __align__(16) unsigned char smem[41*1024];
  unsigned short* lA   = (unsigned short*)smem;
  unsigned short* lB   = (unsigned short*)(smem + 32*1024);
  unsigned short* lA20 = (unsigned short*)smem;
  unsigned short* lB20 = (unsigned short*)(smem + 32*1024);
  float* red           = (float*)smem;
  float* lt            = (float*)(smem + 64);

  int bid = blockIdx.x, tid = threadIdx.x;
  int lane = tid&63, wv = tid>>6, lo = lane&15, hi = lane>>4;
  unsigned crossing = 0;

  if (bid < 128)
    ((f32x4*)(p.xbuf + bid*C_))[tid] = ((const f32x4*)(p.in_BC + bid*C_))[tid];
  gbar(p.bar, crossing);

  for (int l=0; l<12; ++l){
    // ---------- phase 1: tmix ----------
    if (bid < 128){
      int b = bid;
      const float* lnw = p.lntw + l*1024; const float* lnb = p.lntb + l*1024;
      const float* lerp8 = p.lerp8 + l*8192; const float* xs = p.txs + l*131072;
      f32x4 v = ((const f32x4*)(p.xbuf + b*C_))[tid];
      float s = v[0]+v[1]+v[2]+v[3];
      float ss = v[0]*v[0]+v[1]*v[1]+v[2]*v[2]+v[3]*v[3];
      s = wsum(s); ss = wsum(ss);
      if (lane==0){ red[wv]=s; red[4+wv]=ss; }
      __syncthreads();
      float S1 = red[0]+red[1]+red[2]+red[3];
      float S2 = red[4]+red[5]+red[6]+red[7];
      float m = S1*(1.f/C_);
      float var = S2*(1.f/C_) - m*m;
      float inv = rsqrtf(var + 1e-5f);
      int c0 = tid*4;
      float xl[4], xsv[4];
      #pragma unroll
      for(int j=0;j<4;++j){
        xl[j]  = (v[j]-m)*inv*lnw[c0+j] + lnb[c0+j];
        xsv[j] = xs[b*C_ + c0 + j];
      }
      #pragma unroll
      for(int jj=0;jj<8;++jj){
        float o[4];
        #pragma unroll
        for(int j=0;j<4;++j){
          float t = lerp8[jj*C_ + c0 + j];
          o[j] = xl[j] + t*(xsv[j]-xl[j]);
        }
        *(unsigned long long*)&p.mixed[jj*(B_*C_) + b*C_ + c0] = pack4(o[0],o[1],o[2],o[3]);
      }
    }
    gbar(p.bar, crossing);

    // ---------- phase 2: gemm1 (107 tiles x 2 K-slabs) ----------
    if (bid < 214){
      int t = bid >> 1, ksl = bid & 1;
      int wsel, asel, wcol=0, ldw=1024, ocol, wtrans=0, nvalid=32;
      if (t < 96)      { int g=t>>5, s=t&31; wsel=g; asel=g; wcol=s*32; ocol=g*1024+s*32; }
      else if (t==96)  { wsel=3; asel=2; ldw=32;  ocol=3072; }
      else if (t<=98)  { int s=t-97;  wsel=4; asel=4; ldw=64;  wcol=s*32; ocol=3104+s*32; }
      else if (t<=100) { int s=t-99;  wsel=5; asel=3; ldw=64;  wcol=s*32; ocol=3168+s*32; }
      else if (t<=104) { int s=t-101; wsel=6; asel=5; ldw=128; wcol=s*32; ocol=3232+s*32; }
      else if (t==105) { wsel=7; asel=6; wtrans=1; nvalid=16; ocol=3360; }
      else             { wsel=8; asel=7; wtrans=1; nvalid=16; ocol=3376; }
      const float* Wsel =
        wsel==0 ? p.Wr + (size_t)l*1048576 :
        wsel==1 ? p.Wk + (size_t)l*1048576 :
        wsel==2 ? p.Wv + (size_t)l*1048576 :
        wsel==3 ? p.vA + l*32768 :
        wsel==4 ? p.aA + l*65536 :
        wsel==5 ? p.dA + l*65536 :
        wsel==6 ? p.gA + l*131072 :
        wsel==7 ? p.ksW + l*16384 : p.vsW + l*16384;
      gemm32<0,0>(lA,lB, p.mixed + asel*(B_*C_), nullptr, C_, Wsel, ldw, wcol, wtrans,
                  p.g1s + (size_t)ksl*SL1, nullptr, LD1, ocol, nvalid, ksl*512, 8);
    }
    gbar(p.bar, crossing);

    // ---------- phase 3: gemm2 (LoRA-B, 4 groups x 32 tiles) ----------
    if (bid < 128){
      int grp = bid>>5, s = bid&31;
      int Kd, acol, aop; const float* W;
      if (grp==0){ Kd=32;  acol=3072; aop=0; W=p.vB + l*32768; }
      else if (grp==1){ Kd=64; acol=3104; aop=0; W=p.aB + l*65536; }
      else if (grp==2){ Kd=64; acol=3168; aop=1; W=p.dB + l*65536; }
      else { Kd=128; acol=3232; aop=2; W=p.gB + l*131072; }
      int wcol = s*32;
      #pragma unroll
      for (int pp=0;pp<16;++pp){
        int idx = tid + pp*256; int m = idx>>5; int c4 = (idx&31)<<2;
        unsigned long long val = 0ull;
        if (c4 < Kd){
          f32x4 v = *(const f32x4*)&p.g1s[(size_t)m*LD1 + acol + c4];
          f32x4 u = *(const f32x4*)&p.g1s[(size_t)SL1 + (size_t)m*LD1 + acol + c4];
          float e0=v[0]+u[0], e1=v[1]+u[1], e2=v[2]+u[2], e3=v[3]+u[3];
          if (aop==1){ e0=tanhf(e0); e1=tanhf(e1); e2=tanhf(e2); e3=tanhf(e3); }
          else if (aop==2){ e0=sigm(e0); e1=sigm(e1); e2=sigm(e2); e3=sigm(e3); }
          val = pack4(e0,e1,e2,e3);
        }
        *(unsigned long long*)&lA20[swz128(m,c4)] = val;
      }
      int n = tid&31, kp = tid>>5;
      #pragma unroll
      for (int pp=0;pp<8;++pp){
        int kl = pp*16 + kp*2;
        float w0=0.f, w1=0.f;
        if (kl < Kd){ const float* wp = W + (size_t)kl*1024 + wcol + n; w0 = wp[0]; w1 = wp[1024]; }
        unsigned pk = (unsigned)f2bf(w0) | ((unsigned)f2bf(w1)<<16);
        *(unsigned*)&lB20[swz128(n,kl)] = pk;
      }
      __syncthreads();
      f32x4 acc[2][2] = {};
      int w = wv;
      #pragma unroll
      for (int ks=0;ks<4;++ks){
        int kk = ks*32 + hi*8;
        bf16x8 a0 = *(const bf16x8*)&lA20[swz128(w*32+lo, kk)];
        bf16x8 a1 = *(const bf16x8*)&lA20[swz128(w*32+16+lo, kk)];
        #pragma unroll
        for (int nf=0;nf<2;++nf){
          bf16x8 b = *(const bf16x8*)&lB20[swz128(nf*16+lo, kk)];
          acc[0][nf] = __builtin_amdgcn_mfma_f32_16x16x32_bf16(a0,b,acc[0][nf],0,0,0);
          acc[1][nf] = __builtin_amdgcn_mfma_f32_16x16x32_bf16(a1,b,acc[1][nf],0,0,0);
        }
      }
      #pragma unroll
      for (int mf=0;mf<2;++mf)
      #pragma unroll
      for (int nf=0;nf<2;++nf)
      #pragma unroll
      for (int i=0;i<4;++i){
        int row = w*32+mf*16+hi*4+i;
        int c = wcol + nf*16 + lo;
        float x = acc[mf][nf][i];
        int o = row*C_ + c;
        if (grp==3){ p.gfin[o] = x; }
        else if (grp==1){ p.afin[o] = sigm(x + p.abias[l*1024+c]); }
        else if (grp==2){
          float d = x + p.dbias[l*1024+c];
          float sp = log1pf(expf(-d));
          p.wfin[o] = expf(-expf(-0.5f - sp));
        } else {
          p.vm[o] = sigm(x + p.vbias[l*1024+c]);
        }
      }
    }
    gbar(p.bar, crossing);

    // ---------- phase 4: state (2048 pairs = 2 iterations x 256 blocks x 4 waves) ----------
    for (int it=0; it<2; ++it){
      int pair = it*1024 + bid*4 + wv;
      int b = pair>>4, h = pair&15;
      const float* g1r = p.g1s + (size_t)b*LD1;
      int ci = h*64 + lane;
      float r   = g1r[ci]          + g1r[SL1+ci];
      float k   = g1r[1024+ci]     + g1r[SL1+1024+ci];
      float vwv = g1r[2048+ci]     + g1r[SL1+2048+ci];
      float ksc = g1r[3360+h]      + g1r[SL1+3360+h];
      float vsc = g1r[3376+h]      + g1r[SL1+3376+h];
      float v;
      if (l==0){ v = vwv; p.v0[b*C_+ci] = vwv; }
      else { float vmv = p.vm[b*C_+ci]; v = vwv + vmv*(p.v0[b*C_+ci] - vwv); }
      float aa = p.afin[b*C_+ci];
      float ww = p.wfin[b*C_+ci];
      float gg = p.gfin[b*C_+ci];
      float ks = sigm(ksc + p.ksb[l*16+h]);
      float vs = sigm(vsc + p.vsb[l*16+h]);
      float nk = sqrtf(wsum(k*k));
      float kkv = ks * k / fmaxf(nk, 1e-12f);
      float nv = sqrtf(wsum(v*v));
      float vh = vs * v / fmaxf(nv, 1e-12f);
      float kh = kkv * aa;
      float khrh = wsum(kh*r);
      float bkr  = wsum(r * p.bon[l*1024 + h*64+lane] * kh);
      __syncthreads();
      lt[(wv*2+0)*64 + lane] = ww*r;
      lt[(wv*2+1)*64 + lane] = kkv;
      __syncthreads();
      const float* Sr = p.tstate + (size_t)l*8388608 + ((size_t)((b*16+h)*64 + lane))*64;
      float s1=0.f, s2=0.f;
      #pragma unroll
      for (int j=0;j<16;++j){
        f32x4 sv = *(const f32x4*)&Sr[j*4];
        f32x4 u1 = *(const f32x4*)&lt[(wv*2+0)*64 + j*4];
        f32x4 u2 = *(const f32x4*)&lt[(wv*2+1)*64 + j*4];
        s1 += sv[0]*u1[0]+sv[1]*u1[1]+sv[2]*u1[2]+sv[3]*u1[3];
        s2 += sv[0]*u2[0]+sv[1]*u2[1]+sv[2]*u2[2]+sv[3]*u2[3];
      }
      float outv = s1 + (vh - s2)*khrh;
      float mu = wsum(outv)*(1.f/64.f);
      float dev = outv - mu;
      float var = wsum(dev*dev)*(1.f/64.f);
      float gn = dev*rsqrtf(var + 6.4e-4f)*p.gnw[l*1024+ci] + p.gnb[l*1024+ci];
      float yv = gg*(gn + bkr*vh);
      p.ybuf[b*C_+ci] = f2bf(yv);
    }
    gbar(p.bar, crossing);

    // ---------- phase 5: wo (32 tiles x 4 K-splits, atomic onto xbuf) ----------
    if (bid < 128){
      int t = bid&31, ksl = bid>>5;
      gemm32<0,1>(lA,lB, p.ybuf, nullptr, 1024, p.Wo + (size_t)l*1048576, 1024, t*32, 0,
                  p.xbuf, nullptr, 1024, t*32, 32, ksl*256, 4);
    }
    gbar(p.bar, crossing);

    // ---------- phase 6: cmix ----------
    if (bid < 128){
      int b = bid;
      const float* lnw = p.lncw + l*1024; const float* lnb = p.lncb + l*1024;
      const float* lk = p.lkc + l*1024; const float* xs = p.cxs + l*131072;
      f32x4 v = ((const f32x4*)(p.xbuf + b*C_))[tid];
      float s = v[0]+v[1]+v[2]+v[3];
      float ss = v[0]*v[0]+v[1]*v[1]+v[2]*v[2]+v[3]*v[3];
      s = wsum(s); ss = wsum(ss);
      if (lane==0){ red[wv]=s; red[4+wv]=ss; }
      __syncthreads();
      float S1 = red[0]+red[1]+red[2]+red[3];
      float S2 = red[4]+red[5]+red[6]+red[7];
      float m = S1*(1.f/C_);
      float var = S2*(1.f/C_) - m*m;
      float inv = rsqrtf(var + 1e-5f);
      int c0 = tid*4;
      float o[4];
      #pragma unroll
      for(int j=0;j<4;++j){
        float xl = (v[j]-m)*inv*lnw[c0+j] + lnb[c0+j];
        float t = lk[c0+j];
        o[j] = xl + t*(xs[b*C_+c0+j]-xl);
      }
      *(unsigned long long*)&p.mixc[b*C_ + c0] = pack4(o[0],o[1],o[2],o[3]);
    }
    gbar(p.bar, crossing);

    // ---------- phase 7: cwk (128 tiles x 2 K-slabs -> bf16 h slabs) ----------
    {
      int t = bid&127, ksl = bid>>7;
      gemm32<0,2>(lA,lB, p.mixc, nullptr, 1024, p.cWk + (size_t)l*4194304, 4096, t*32, 0,
                  nullptr, p.hs + (size_t)ksl*(B_*4096), 4096, t*32, 32, ksl*512, 8);
    }
    gbar(p.bar, crossing);

    // ---------- phase 8: cwv (32 tiles x 8 K-splits, relu^2(h0+h1), atomic onto xbuf) ----------
    {
      int t = bid&31, ksl = bid>>5;
      gemm32<1,1>(lA,lB, p.hs, p.hs + (size_t)B_*4096, 4096, p.cWv + (size_t)l*4194304, 1024, t*32, 0,
                  p.xbuf, nullptr, 1024, t*32, 32, ksl*512, 8);
    }
    gbar(p.bar, crossing);
  }

  if (bid < 128)
    ((f32x4*)(p.out + bid*C_))[tid] = ((const f32x4*)(p.xbuf + bid*C_))[tid];
}

extern "C" void kernel_launch(void* const* d_in, const int* in_sizes, int n_in,
                              void* d_out, int out_size, void* d_ws, size_t ws_size,
                              hipStream_t stream){
  Par p;
  p.in_BC = (const float*)d_in[0];
  p.txs   = (const float*)d_in[1];
  p.tstate= (const float*)d_in[2];
  p.cxs   = (const float*)d_in[3];
  p.lntw  = (const float*)d_in[4];
  p.lntb  = (const float*)d_in[5];
  p.lerp8 = (const float*)d_in[6];
  p.bon   = (const float*)d_in[7];
  p.Wr    = (const float*)d_in[8];
  p.Wk    = (const float*)d_in[9];
  p.Wv    = (const float*)d_in[10];
  p.Wo    = (const float*)d_in[11];
  p.ksW   = (const float*)d_in[12];
  p.ksb   = (const float*)d_in[13];
  p.vsW   = (const float*)d_in[14];
  p.vsb   = (const float*)d_in[15];
  p.vA    = (const float*)d_in[16];
  p.vB    = (const float*)d_in[17];
  p.vbias = (const float*)d_in[18];
  p.aA    = (const float*)d_in[19];
  p.aB    = (const float*)d_in[20];
  p.abias = (const float*)d_in[21];
  p.dA    = (const float*)d_in[22];
  p.dB    = (const float*)d_in[23];
  p.dbias = (const float*)d_in[24];
  p.gA    = (const float*)d_in[25];
  p.gB    = (const float*)d_in[26];
  p.gnw   = (const float*)d_in[27];
  p.gnb   = (const float*)d_in[28];
  p.lncw  = (const float*)d_in[29];
  p.lncb  = (const float*)d_in[30];
  p.lkc   = (const float*)d_in[31];
  p.cWk   = (const float*)d_in[32];
  p.cWv   = (const float*)d_in[33];
  p.out   = (float*)d_out;

  char* ws = (char*)d_ws;
  p.xbuf  = (float*)(ws + 0x000000);                  // 512K
  p.mixed = (unsigned short*)(ws + 0x080000);         // 2M
  p.g1s   = (float*)(ws + 0x280000);                  // 2 x 0x1A8000
  p.vm    = (float*)(ws + 0x5D0000);                  // 512K
  p.afin  = (float*)(ws + 0x650000);                  // 512K
  p.wfin  = (float*)(ws + 0x6D0000);                  // 512K
  p.gfin  = (float*)(ws + 0x750000);                  // 512K
  p.v0    = (float*)(ws + 0x7D0000);                  // 512K
  p.ybuf  = (unsigned short*)(ws + 0x850000);         // 256K
  p.mixc  = (unsigned short*)(ws + 0x890000);         // 256K
  p.hs    = (unsigned short*)(ws + 0x8D0000);         // 2 x 1M
  p.bar   = (unsigned*)(ws + 0xAD0000);               // 4B barrier counter

  hipMemsetAsync(p.bar, 0, 4, stream);
  net_k<<<NBLK, 256, 0, stream>>>(p);
}

// Round 9
// 3368.844 us; speedup vs baseline: 1.9872x; 1.9872x over previous
//
#include <hip/hip_runtime.h>
#include <hip/hip_bf16.h>

#define B_ 128
#define C_ 1024
#define LD1 3392
#define SL1 (B_*LD1)
#define NBLK 256

typedef float f32x4 __attribute__((ext_vector_type(4)));
typedef short bf16x8 __attribute__((ext_vector_type(8)));

__device__ inline unsigned short f2bf(float x){
  unsigned u = __float_as_uint(x);
  return (unsigned short)((u + 0x7fffu + ((u>>16)&1u)) >> 16);
}
__device__ inline unsigned long long pack4(float a,float b,float c,float d){
  unsigned lo = (unsigned)f2bf(a) | ((unsigned)f2bf(b)<<16);
  unsigned hi = (unsigned)f2bf(c) | ((unsigned)f2bf(d)<<16);
  return (unsigned long long)lo | ((unsigned long long)hi<<32);
}
__device__ inline float bf2f(unsigned short b){ return __uint_as_float(((unsigned)b)<<16); }
__device__ inline float sigm(float x){ return 1.f/(1.f+expf(-x)); }
__device__ inline float wsum(float v){
  #pragma unroll
  for(int o=32;o;o>>=1) v += __shfl_xor(v,o);
  return v;
}
__device__ inline int swz64(int r,int c){ return (r*64+c) ^ ((r&7)<<3); }
__device__ inline int swz128(int r,int c){ return (r*128+c) ^ ((r&7)<<3); }

struct Par {
  const float *in_BC,*txs,*tstate,*cxs,*lntw,*lntb,*lerp8,*bon;
  const float *Wr,*Wk,*Wv,*Wo,*ksW,*ksb,*vsW,*vsb;
  const float *vA,*vB,*vbias,*aA,*aB,*abias,*dA,*dB,*dbias,*gA,*gB;
  const float *gnw,*gnb,*lncw,*lncb,*lkc,*cWk,*cWv;
  float *out;
  float *xbuf,*g1s,*vm,*afin,*wfin,*gfin,*v0;
  unsigned short *mixed,*ybuf,*mixc,*hs;
  unsigned *bar;
};

// ---- broadcast grid barrier: 1 counter (single poller) + 8 go-lines (<=32 pollers each) ----
#define GO_STRIDE 32   // u32 units -> 128B per line
__device__ __forceinline__ void gbar(unsigned* bar, unsigned& crossing, int bid){
  __syncthreads();
  if (threadIdx.x == 0){
    __threadfence();                           // release this block's phase writes
    atomicAdd(&bar[0], 1u);
    ++crossing;
    if (bid == 0){
      while (__hip_atomic_load(&bar[0], __ATOMIC_RELAXED, __HIP_MEMORY_SCOPE_AGENT)
             < NBLK*crossing)
        __builtin_amdgcn_s_sleep(8);
      __threadfence();                         // acquire all blocks' writes, release for go
      #pragma unroll
      for (int g=0; g<8; ++g)
        __hip_atomic_store(&bar[(1+g)*GO_STRIDE], crossing,
                           __ATOMIC_RELAXED, __HIP_MEMORY_SCOPE_AGENT);
    } else {
      unsigned* go = &bar[(1+(bid&7))*GO_STRIDE];
      while (__hip_atomic_load(go, __ATOMIC_RELAXED, __HIP_MEMORY_SCOPE_AGENT) < crossing)
        __builtin_amdgcn_s_sleep(16);
    }
    __threadfence();                           // acquire before consuming
  }
  __syncthreads();
}

// ---- r1-proven direct-stage GEMM core: M=128, N=32, BK=64 ----
// AMODE 0: A bf16.  AMODE 1: A = relu^2(bf16 slab0 + bf16 slab1).
// OUTM 0: f32 store. 1: f32 atomic-add. 2: bf16 store.
template<int AMODE, int OUTM>
__device__ void gemm32(unsigned short* lA, unsigned short* lB,
    const unsigned short* __restrict__ A0, const unsigned short* __restrict__ A1, int lda,
    const float* __restrict__ W, int ldw, int wcol, int wtrans,
    float* __restrict__ outf, unsigned short* __restrict__ out16,
    int ldo, int ocol, int nvalid, int kt0, int kIters)
{
  int tid=threadIdx.x, lane=tid&63, w=tid>>6, lo=lane&15, hi=lane>>4;
  f32x4 acc[2][2] = {};
  for (int kb=0;kb<kIters;++kb){
    int k0 = kt0 + kb*64;
    #pragma unroll
    for (int p=0;p<8;++p){
      int idx = tid + p*256; int m = idx>>4; int c4 = (idx&15)<<2;
      unsigned long long v;
      if constexpr (AMODE==1){
        unsigned long long u0 = *(const unsigned long long*)(A0 + (size_t)m*lda + k0 + c4);
        unsigned long long u1 = *(const unsigned long long*)(A1 + (size_t)m*lda + k0 + c4);
        float e[4];
        #pragma unroll
        for (int j=0;j<4;++j){
          float s = bf2f((unsigned short)(u0>>(16*j))) + bf2f((unsigned short)(u1>>(16*j)));
          s = fmaxf(s,0.f); e[j] = s*s;
        }
        v = pack4(e[0],e[1],e[2],e[3]);
      } else {
        v = *(const unsigned long long*)(A0 + (size_t)m*lda + k0 + c4);
      }
      *(unsigned long long*)&lA[swz64(m,c4)] = v;
    }
    int n = tid&31, kp = tid>>5;
    #pragma unroll
    for (int p=0;p<4;++p){
      int kl = p*16 + kp*2;
      float w0=0.f, w1=0.f;
      if (!wtrans){
        const float* wp = W + (size_t)(k0+kl)*ldw + wcol + n;
        w0 = wp[0]; w1 = wp[ldw];
      } else if (n < 16){
        const float* wp = W + (size_t)n*1024 + k0 + kl;
        w0 = wp[0]; w1 = wp[1];
      }
      unsigned pk = (unsigned)f2bf(w0) | ((unsigned)f2bf(w1)<<16);
      *(unsigned*)&lB[swz64(n,kl)] = pk;
    }
    __syncthreads();
    #pragma unroll
    for (int ks=0;ks<2;++ks){
      int kk = ks*32 + hi*8;
      bf16x8 a0 = *(const bf16x8*)&lA[swz64(w*32+lo, kk)];
      bf16x8 a1 = *(const bf16x8*)&lA[swz64(w*32+16+lo, kk)];
      bf16x8 b0 = *(const bf16x8*)&lB[swz64(lo, kk)];
      bf16x8 b1 = *(const bf16x8*)&lB[swz64(16+lo, kk)];
      acc[0][0] = __builtin_amdgcn_mfma_f32_16x16x32_bf16(a0,b0,acc[0][0],0,0,0);
      acc[0][1] = __builtin_amdgcn_mfma_f32_16x16x32_bf16(a0,b1,acc[0][1],0,0,0);
      acc[1][0] = __builtin_amdgcn_mfma_f32_16x16x32_bf16(a1,b0,acc[1][0],0,0,0);
      acc[1][1] = __builtin_amdgcn_mfma_f32_16x16x32_bf16(a1,b1,acc[1][1],0,0,0);
    }
    __syncthreads();
  }
  #pragma unroll
  for (int mf=0;mf<2;++mf)
  #pragma unroll
  for (int nf=0;nf<2;++nf){
    int cl = nf*16 + lo;
    if (cl < nvalid){
      #pragma unroll
      for (int i=0;i<4;++i){
        int row = w*32 + mf*16 + hi*4 + i;
        size_t o = (size_t)row*ldo + ocol + cl;
        if constexpr (OUTM==0) outf[o] = acc[mf][nf][i];
        else if constexpr (OUTM==1) unsafeAtomicAdd(&outf[o], acc[mf][nf][i]);
        else out16[o] = f2bf(acc[mf][nf][i]);
      }
    }
  }
}

__global__ void __launch_bounds__(256) net_k(Par p){
  __shared__ __align__(16) unsigned char smem[41*1024];
  unsigned short* lA   = (unsigned short*)smem;
  unsigned short* lB   = (unsigned short*)(smem + 32*1024);
  unsigned short* lA20 = (unsigned short*)smem;
  unsigned short* lB20 = (unsigned short*)(smem + 32*1024);
  float* red           = (float*)smem;
  float* lt            = (float*)(smem + 64);

  int bid = blockIdx.x, tid = threadIdx.x;
  int lane = tid&63, wv = tid>>6, lo = lane&15, hi = lane>>4;
  unsigned crossing = 0;

  if (bid < 128)
    ((f32x4*)(p.xbuf + bid*C_))[tid] = ((const f32x4*)(p.in_BC + bid*C_))[tid];
  gbar(p.bar, crossing, bid);

  for (int l=0; l<12; ++l){
    // ---------- phase 1: tmix ----------
    if (bid < 128){
      int b = bid;
      const float* lnw = p.lntw + l*1024; const float* lnb = p.lntb + l*1024;
      const float* lerp8 = p.lerp8 + l*8192; const float* xs = p.txs + l*131072;
      f32x4 v = ((const f32x4*)(p.xbuf + b*C_))[tid];
      float s = v[0]+v[1]+v[2]+v[3];
      float ss = v[0]*v[0]+v[1]*v[1]+v[2]*v[2]+v[3]*v[3];
      s = wsum(s); ss = wsum(ss);
      if (lane==0){ red[wv]=s; red[4+wv]=ss; }
      __syncthreads();
      float S1 = red[0]+red[1]+red[2]+red[3];
      float S2 = red[4]+red[5]+red[6]+red[7];
      float m = S1*(1.f/C_);
      float var = S2*(1.f/C_) - m*m;
      float inv = rsqrtf(var + 1e-5f);
      int c0 = tid*4;
      float xl[4], xsv[4];
      #pragma unroll
      for(int j=0;j<4;++j){
        xl[j]  = (v[j]-m)*inv*lnw[c0+j] + lnb[c0+j];
        xsv[j] = xs[b*C_ + c0 + j];
      }
      #pragma unroll
      for(int jj=0;jj<8;++jj){
        float o[4];
        #pragma unroll
        for(int j=0;j<4;++j){
          float t = lerp8[jj*C_ + c0 + j];
          o[j] = xl[j] + t*(xsv[j]-xl[j]);
        }
        *(unsigned long long*)&p.mixed[jj*(B_*C_) + b*C_ + c0] = pack4(o[0],o[1],o[2],o[3]);
      }
    }
    gbar(p.bar, crossing, bid);

    // ---------- phase 2: gemm1 (107 tiles x 2 K-slabs) ----------
    if (bid < 214){
      int t = bid >> 1, ksl = bid & 1;
      int wsel, asel, wcol=0, ldw=1024, ocol, wtrans=0, nvalid=32;
      if (t < 96)      { int g=t>>5, s=t&31; wsel=g; asel=g; wcol=s*32; ocol=g*1024+s*32; }
      else if (t==96)  { wsel=3; asel=2; ldw=32;  ocol=3072; }
      else if (t<=98)  { int s=t-97;  wsel=4; asel=4; ldw=64;  wcol=s*32; ocol=3104+s*32; }
      else if (t<=100) { int s=t-99;  wsel=5; asel=3; ldw=64;  wcol=s*32; ocol=3168+s*32; }
      else if (t<=104) { int s=t-101; wsel=6; asel=5; ldw=128; wcol=s*32; ocol=3232+s*32; }
      else if (t==105) { wsel=7; asel=6; wtrans=1; nvalid=16; ocol=3360; }
      else             { wsel=8; asel=7; wtrans=1; nvalid=16; ocol=3376; }
      const float* Wsel =
        wsel==0 ? p.Wr + (size_t)l*1048576 :
        wsel==1 ? p.Wk + (size_t)l*1048576 :
        wsel==2 ? p.Wv + (size_t)l*1048576 :
        wsel==3 ? p.vA + l*32768 :
        wsel==4 ? p.aA + l*65536 :
        wsel==5 ? p.dA + l*65536 :
        wsel==6 ? p.gA + l*131072 :
        wsel==7 ? p.ksW + l*16384 : p.vsW + l*16384;
      gemm32<0,0>(lA,lB, p.mixed + asel*(B_*C_), nullptr, C_, Wsel, ldw, wcol, wtrans,
                  p.g1s + (size_t)ksl*SL1, nullptr, LD1, ocol, nvalid, ksl*512, 8);
    }
    gbar(p.bar, crossing, bid);

    // ---------- phase 3: gemm2 (LoRA-B, 4 groups x 32 tiles) ----------
    if (bid < 128){
      int grp = bid>>5, s = bid&31;
      int Kd, acol, aop; const float* W;
      if (grp==0){ Kd=32;  acol=3072; aop=0; W=p.vB + l*32768; }
      else if (grp==1){ Kd=64; acol=3104; aop=0; W=p.aB + l*65536; }
      else if (grp==2){ Kd=64; acol=3168; aop=1; W=p.dB + l*65536; }
      else { Kd=128; acol=3232; aop=2; W=p.gB + l*131072; }
      int wcol = s*32;
      #pragma unroll
      for (int pp=0;pp<16;++pp){
        int idx = tid + pp*256; int m = idx>>5; int c4 = (idx&31)<<2;
        unsigned long long val = 0ull;
        if (c4 < Kd){
          f32x4 v = *(const f32x4*)&p.g1s[(size_t)m*LD1 + acol + c4];
          f32x4 u = *(const f32x4*)&p.g1s[(size_t)SL1 + (size_t)m*LD1 + acol + c4];
          float e0=v[0]+u[0], e1=v[1]+u[1], e2=v[2]+u[2], e3=v[3]+u[3];
          if (aop==1){ e0=tanhf(e0); e1=tanhf(e1); e2=tanhf(e2); e3=tanhf(e3); }
          else if (aop==2){ e0=sigm(e0); e1=sigm(e1); e2=sigm(e2); e3=sigm(e3); }
          val = pack4(e0,e1,e2,e3);
        }
        *(unsigned long long*)&lA20[swz128(m,c4)] = val;
      }
      int n = tid&31, kp = tid>>5;
      #pragma unroll
      for (int pp=0;pp<8;++pp){
        int kl = pp*16 + kp*2;
        float w0=0.f, w1=0.f;
        if (kl < Kd){ const float* wp = W + (size_t)kl*1024 + wcol + n; w0 = wp[0]; w1 = wp[1024]; }
        unsigned pk = (unsigned)f2bf(w0) | ((unsigned)f2bf(w1)<<16);
        *(unsigned*)&lB20[swz128(n,kl)] = pk;
      }
      __syncthreads();
      f32x4 acc[2][2] = {};
      int w = wv;
      #pragma unroll
      for (int ks=0;ks<4;++ks){
        int kk = ks*32 + hi*8;
        bf16x8 a0 = *(const bf16x8*)&lA20[swz128(w*32+lo, kk)];
        bf16x8 a1 = *(const bf16x8*)&lA20[swz128(w*32+16+lo, kk)];
        #pragma unroll
        for (int nf=0;nf<2;++nf){
          bf16x8 b = *(const bf16x8*)&lB20[swz128(nf*16+lo, kk)];
          acc[0][nf] = __builtin_amdgcn_mfma_f32_16x16x32_bf16(a0,b,acc[0][nf],0,0,0);
          acc[1][nf] = __builtin_amdgcn_mfma_f32_16x16x32_bf16(a1,b,acc[1][nf],0,0,0);
        }
      }
      #pragma unroll
      for (int mf=0;mf<2;++mf)
      #pragma unroll
      for (int nf=0;nf<2;++nf)
      #pragma unroll
      for (int i=0;i<4;++i){
        int row = w*32+mf*16+hi*4+i;
        int c = wcol + nf*16 + lo;
        float x = acc[mf][nf][i];
        int o = row*C_ + c;
        if (grp==3){ p.gfin[o] = x; }
        else if (grp==1){ p.afin[o] = sigm(x + p.abias[l*1024+c]); }
        else if (grp==2){
          float d = x + p.dbias[l*1024+c];
          float sp = log1pf(expf(-d));
          p.wfin[o] = expf(-expf(-0.5f - sp));
        } else {
          p.vm[o] = sigm(x + p.vbias[l*1024+c]);
        }
      }
    }
    gbar(p.bar, crossing, bid);

    // ---------- phase 4: state (2048 pairs = 2 iterations x 256 blocks x 4 waves) ----------
    for (int it=0; it<2; ++it){
      int pair = it*1024 + bid*4 + wv;
      int b = pair>>4, h = pair&15;
      const float* g1r = p.g1s + (size_t)b*LD1;
      int ci = h*64 + lane;
      float r   = g1r[ci]          + g1r[SL1+ci];
      float k   = g1r[1024+ci]     + g1r[SL1+1024+ci];
      float vwv = g1r[2048+ci]     + g1r[SL1+2048+ci];
      float ksc = g1r[3360+h]      + g1r[SL1+3360+h];
      float vsc = g1r[3376+h]      + g1r[SL1+3376+h];
      float v;
      if (l==0){ v = vwv; p.v0[b*C_+ci] = vwv; }
      else { float vmv = p.vm[b*C_+ci]; v = vwv + vmv*(p.v0[b*C_+ci] - vwv); }
      float aa = p.afin[b*C_+ci];
      float ww = p.wfin[b*C_+ci];
      float gg = p.gfin[b*C_+ci];
      float ks = sigm(ksc + p.ksb[l*16+h]);
      float vs = sigm(vsc + p.vsb[l*16+h]);
      float nk = sqrtf(wsum(k*k));
      float kkv = ks * k / fmaxf(nk, 1e-12f);
      float nv = sqrtf(wsum(v*v));
      float vh = vs * v / fmaxf(nv, 1e-12f);
      float kh = kkv * aa;
      float khrh = wsum(kh*r);
      float bkr  = wsum(r * p.bon[l*1024 + h*64+lane] * kh);
      __syncthreads();
      lt[(wv*2+0)*64 + lane] = ww*r;
      lt[(wv*2+1)*64 + lane] = kkv;
      __syncthreads();
      const float* Sr = p.tstate + (size_t)l*8388608 + ((size_t)((b*16+h)*64 + lane))*64;
      float s1=0.f, s2=0.f;
      #pragma unroll
      for (int j=0;j<16;++j){
        f32x4 sv = *(const f32x4*)&Sr[j*4];
        f32x4 u1 = *(const f32x4*)&lt[(wv*2+0)*64 + j*4];
        f32x4 u2 = *(const f32x4*)&lt[(wv*2+1)*64 + j*4];
        s1 += sv[0]*u1[0]+sv[1]*u1[1]+sv[2]*u1[2]+sv[3]*u1[3];
        s2 += sv[0]*u2[0]+sv[1]*u2[1]+sv[2]*u2[2]+sv[3]*u2[3];
      }
      float outv = s1 + (vh - s2)*khrh;
      float mu = wsum(outv)*(1.f/64.f);
      float dev = outv - mu;
      float var = wsum(dev*dev)*(1.f/64.f);
      float gn = dev*rsqrtf(var + 6.4e-4f)*p.gnw[l*1024+ci] + p.gnb[l*1024+ci];
      float yv = gg*(gn + bkr*vh);
      p.ybuf[b*C_+ci] = f2bf(yv);
    }
    gbar(p.bar, crossing, bid);

    // ---------- phase 5: wo (32 tiles x 4 K-splits, atomic onto xbuf) ----------
    if (bid < 128){
      int t = bid&31, ksl = bid>>5;
      gemm32<0,1>(lA,lB, p.ybuf, nullptr, 1024, p.Wo + (size_t)l*1048576, 1024, t*32, 0,
                  p.xbuf, nullptr, 1024, t*32, 32, ksl*256, 4);
    }
    gbar(p.bar, crossing, bid);

    // ---------- phase 6: cmix ----------
    if (bid < 128){
      int b = bid;
      const float* lnw = p.lncw + l*1024; const float* lnb = p.lncb + l*1024;
      const float* lk = p.lkc + l*1024; const float* xs = p.cxs + l*131072;
      f32x4 v = ((const f32x4*)(p.xbuf + b*C_))[tid];
      float s = v[0]+v[1]+v[2]+v[3];
      float ss = v[0]*v[0]+v[1]*v[1]+v[2]*v[2]+v[3]*v[3];
      s = wsum(s); ss = wsum(ss);
      if (lane==0){ red[wv]=s; red[4+wv]=ss; }
      __syncthreads();
      float S1 = red[0]+red[1]+red[2]+red[3];
      float S2 = red[4]+red[5]+red[6]+red[7];
      float m = S1*(1.f/C_);
      float var = S2*(1.f/C_) - m*m;
      float inv = rsqrtf(var + 1e-5f);
      int c0 = tid*4;
      float o[4];
      #pragma unroll
      for(int j=0;j<4;++j){
        float xl = (v[j]-m)*inv*lnw[c0+j] + lnb[c0+j];
        float t = lk[c0+j];
        o[j] = xl + t*(xs[b*C_+c0+j]-xl);
      }
      *(unsigned long long*)&p.mixc[b*C_ + c0] = pack4(o[0],o[1],o[2],o[3]);
    }
    gbar(p.bar, crossing, bid);

    // ---------- phase 7: cwk (128 tiles x 2 K-slabs -> bf16 h slabs) ----------
    {
      int t = bid&127, ksl = bid>>7;
      gemm32<0,2>(lA,lB, p.mixc, nullptr, 1024, p.cWk + (size_t)l*4194304, 4096, t*32, 0,
                  nullptr, p.hs + (size_t)ksl*(B_*4096), 4096, t*32, 32, ksl*512, 8);
    }
    gbar(p.bar, crossing, bid);

    // ---------- phase 8: cwv (32 tiles x 8 K-splits, relu^2(h0+h1), atomic onto xbuf) ----------
    {
      int t = bid&31, ksl = bid>>5;
      gemm32<1,1>(lA,lB, p.hs, p.hs + (size_t)B_*4096, 4096, p.cWv + (size_t)l*4194304, 1024, t*32, 0,
                  p.xbuf, nullptr, 1024, t*32, 32, ksl*512, 8);
    }
    gbar(p.bar, crossing, bid);
  }

  if (bid < 128)
    ((f32x4*)(p.out + bid*C_))[tid] = ((const f32x4*)(p.xbuf + bid*C_))[tid];
}

extern "C" void kernel_launch(void* const* d_in, const int* in_sizes, int n_in,
                              void* d_out, int out_size, void* d_ws, size_t ws_size,
                              hipStream_t stream){
  Par p;
  p.in_BC = (const float*)d_in[0];
  p.txs   = (const float*)d_in[1];
  p.tstate= (const float*)d_in[2];
  p.cxs   = (const float*)d_in[3];
  p.lntw  = (const float*)d_in[4];
  p.lntb  = (const float*)d_in[5];
  p.lerp8 = (const float*)d_in[6];
  p.bon   = (const float*)d_in[7];
  p.Wr    = (const float*)d_in[8];
  p.Wk    = (const float*)d_in[9];
  p.Wv    = (const float*)d_in[10];
  p.Wo    = (const float*)d_in[11];
  p.ksW   = (const float*)d_in[12];
  p.ksb   = (const float*)d_in[13];
  p.vsW   = (const float*)d_in[14];
  p.vsb   = (const float*)d_in[15];
  p.vA    = (const float*)d_in[16];
  p.vB    = (const float*)d_in[17];
  p.vbias = (const float*)d_in[18];
  p.aA    = (const float*)d_in[19];
  p.aB    = (const float*)d_in[20];
  p.abias = (const float*)d_in[21];
  p.dA    = (const float*)d_in[22];
  p.dB    = (const float*)d_in[23];
  p.dbias = (const float*)d_in[24];
  p.gA    = (const float*)d_in[25];
  p.gB    = (const float*)d_in[26];
  p.gnw   = (const float*)d_in[27];
  p.gnb   = (const float*)d_in[28];
  p.lncw  = (const float*)d_in[29];
  p.lncb  = (const float*)d_in[30];
  p.lkc   = (const float*)d_in[31];
  p.cWk   = (const float*)d_in[32];
  p.cWv   = (const float*)d_in[33];
  p.out   = (float*)d_out;

  char* ws = (char*)d_ws;
  p.xbuf  = (float*)(ws + 0x000000);                  // 512K
  p.mixed = (unsigned short*)(ws + 0x080000);         // 2M
  p.g1s   = (float*)(ws + 0x280000);                  // 2 x 0x1A8000
  p.vm    = (float*)(ws + 0x5D0000);                  // 512K
  p.afin  = (float*)(ws + 0x650000);                  // 512K
  p.wfin  = (float*)(ws + 0x6D0000);                  // 512K
  p.gfin  = (float*)(ws + 0x750000);                  // 512K
  p.v0    = (float*)(ws + 0x7D0000);                  // 512K
  p.ybuf  = (unsigned short*)(ws + 0x850000);         // 256K
  p.mixc  = (unsigned short*)(ws + 0x890000);         // 256K
  p.hs    = (unsigned short*)(ws + 0x8D0000);         // 2 x 1M
  p.bar   = (unsigned*)(ws + 0xAD0000);               // 9 x 128B barrier lines

  hipMemsetAsync(p.bar, 0, 4096, stream);
  net_k<<<NBLK, 256, 0, stream>>>(p);
}